// Round 1
// baseline (577.316 us; speedup 1.0000x reference)
//
#include <hip/hip_runtime.h>

// MaxPool2d 2x2 stride 1 VALID, NCHW fp32.
// In:  (16, 96, 224, 224)  Out: (16, 96, 223, 223)

#define W_IN   224
#define HW_IN  (224 * 224)
#define W_OUT  223
#define H_OUT  223

__global__ __launch_bounds__(256) void maxpool2x2_s1_kernel(
    const float* __restrict__ in, float* __restrict__ out, int total) {
  int idx = blockIdx.x * 256 + threadIdx.x;
  if (idx >= total) return;

  // idx -> (nc, h, w) over output
  int w  = idx % W_OUT;
  int t  = idx / W_OUT;
  int h  = t % H_OUT;
  int nc = t / H_OUT;

  const float* p = in + (size_t)nc * HW_IN + h * W_IN + w;
  float m0 = fmaxf(p[0], p[1]);
  float m1 = fmaxf(p[W_IN], p[W_IN + 1]);
  out[idx] = fmaxf(m0, m1);
}

extern "C" void kernel_launch(void* const* d_in, const int* in_sizes, int n_in,
                              void* d_out, int out_size, void* d_ws, size_t ws_size,
                              hipStream_t stream) {
  const float* x = (const float*)d_in[0];
  float* out = (float*)d_out;
  const int total = 16 * 96 * H_OUT * W_OUT;  // 76,384,224
  const int blocks = (total + 255) / 256;
  maxpool2x2_s1_kernel<<<blocks, 256, 0, stream>>>(x, out, total);
}

// Round 2
// 533.431 us; speedup vs baseline: 1.0823x; 1.0823x over previous
//
#include <hip/hip_runtime.h>

// MaxPool2d 2x2 stride 1 VALID, NCHW fp32.
// In:  (16, 96, 224, 224)  Out: (16, 96, 223, 223)
// 4 outputs per thread, vectorized loads/stores.

#define W_IN   224
#define HW_IN  (224 * 224)
#define W_OUT  223
#define H_OUT  223

typedef float f4a __attribute__((ext_vector_type(4)));                 // 16B-aligned
typedef float f4u __attribute__((ext_vector_type(4), aligned(4)));     // dword-aligned

__global__ __launch_bounds__(256) void maxpool2x2_s1_v4_kernel(
    const float* __restrict__ in, float* __restrict__ out, int total4) {
  int t = blockIdx.x * 256 + threadIdx.x;
  if (t >= total4) return;

  int base = t * 4;                 // first of 4 consecutive flat output indices
  int w  = base % W_OUT;
  int r  = base / W_OUT;            // row index over (nc*H_OUT + h)

  if (w <= W_OUT - 4) {
    // all 4 outputs in the same row: need in[p..p+4] and in[p+224..p+228]
    int h  = r % H_OUT;
    int nc = r / H_OUT;
    const float* p = in + (size_t)nc * HW_IN + h * W_IN + w;
    f4u a = *(const f4u*)p;
    float a4 = p[4];
    f4u b = *(const f4u*)(p + W_IN);
    float b4 = p[W_IN + 4];

    f4a o;
    o.x = fmaxf(fmaxf(a.x, a.y), fmaxf(b.x, b.y));
    o.y = fmaxf(fmaxf(a.y, a.z), fmaxf(b.y, b.z));
    o.z = fmaxf(fmaxf(a.z, a.w), fmaxf(b.z, b.w));
    o.w = fmaxf(fmaxf(a.w, a4),  fmaxf(b.w, b4));
    *(f4a*)(out + base) = o;
  } else {
    // straddles a row (and possibly image) boundary: scalar per output
    f4a o;
    #pragma unroll
    for (int j = 0; j < 4; ++j) {
      int idx = base + j;
      int wj  = idx % W_OUT;
      int tj  = idx / W_OUT;
      int hj  = tj % H_OUT;
      int ncj = tj / H_OUT;
      const float* p = in + (size_t)ncj * HW_IN + hj * W_IN + wj;
      float m0 = fmaxf(p[0], p[1]);
      float m1 = fmaxf(p[W_IN], p[W_IN + 1]);
      ((float*)&o)[j] = fmaxf(m0, m1);
    }
    *(f4a*)(out + base) = o;  // base is 16B-aligned; 4 outputs always exist (total % 4 == 0)
  }
}

extern "C" void kernel_launch(void* const* d_in, const int* in_sizes, int n_in,
                              void* d_out, int out_size, void* d_ws, size_t ws_size,
                              hipStream_t stream) {
  const float* x = (const float*)d_in[0];
  float* out = (float*)d_out;
  const int total = 16 * 96 * H_OUT * W_OUT;  // 76,384,224 (divisible by 4)
  const int total4 = total / 4;               // 19,096,056
  const int blocks = (total4 + 255) / 256;
  maxpool2x2_s1_v4_kernel<<<blocks, 256, 0, stream>>>(x, out, total4);
}